// Round 8
// baseline (57.064 us; speedup 1.0000x reference)
//
#include <hip/hip_runtime.h>

// out[b, t, w, c] = x[b, t + w - 9, c] (zero outside [0, T)), x: [32, 4096, 30] f32.
// Per (b,t) the 570-float output row equals the contiguous x span starting at
// (t-9)*30. Row-pair (t even) = 1140 floats = 285 float4 units, 16B-aligned.
// R6: 4KB/wave stream clustering -> 56.2us. R7: 8KB/wave == 4KB (saturated).
// This round: bijective XCD swizzle (each XCD gets a contiguous 1/8 of the
// output, so its x working set ~2MB fits the 4MB per-XCD L2; reads move from
// L3 to L2) + nontemporal stores (R5: perf-neutral) so the write stream does
// not evict x from L2.

typedef float f32x4 __attribute__((ext_vector_type(4)));

constexpr int B   = 32;
constexpr int T   = 4096;          // power of 2
constexpr int C   = 30;
constexpr int PAD = 9;             // W/2
constexpr int ROW = 570;           // W*C floats per output row
constexpr int TC  = T * C;         // 122880 floats per batch of x
constexpr int PAIR_F4 = 285;       // float4 units per row-pair (1140 floats)
constexpr unsigned NPAIRS = (unsigned)B * (T / 2);   // 65536 row-pairs
constexpr unsigned TOTAL4 = NPAIRS * PAIR_F4;        // 18,662,400 float4 units
constexpr int UNROLL = 4;          // wave covers 256 units = 4KB sequential
constexpr unsigned NWG = TOTAL4 / 1024;  // 18,225 blocks (256 thr = 1024 units)
// Bijective XCD swizzle (m204): NWG = 8*q + r, q=2278, r=1.
constexpr unsigned XQ = NWG / 8;   // 2278
constexpr unsigned XR = NWG % 8;   // 1

__global__ __launch_bounds__(256)
void OverlapTimeWindowLayer_kernel(const float* __restrict__ x,
                                   f32x4* __restrict__ out) {
    // Remap dispatch id -> logical block so each XCD (= dispatch%8) sweeps a
    // contiguous chunk of the output. Scalar math, wave-uniform.
    const unsigned orig = blockIdx.x;
    const unsigned xcd  = orig & 7u;
    const unsigned idx  = orig >> 3;
    const unsigned lb   = (xcd < XR ? xcd * (XQ + 1u)
                                    : XR * (XQ + 1u) + (xcd - XR) * XQ) + idx;

    const unsigned wave = lb * 4u + (threadIdx.x >> 6);
    const int      lane = (int)(threadIdx.x & 63u);
    const unsigned vbase = wave * 256u + (unsigned)lane;  // unit for k=0
#pragma unroll
    for (int k = 0; k < UNROLL; ++k) {
        const unsigned v = vbase + (unsigned)(64 * k);  // wave-contiguous 1KB each
        const unsigned p = v / PAIR_F4;            // row-pair index (magic-mul div)
        const int u  = (int)(v - p * PAIR_F4);     // float4 unit within pair [0,285)
        const int b  = (int)(p >> 11);             // / (T/2)
        const int tp = (int)(p & 2047);            // pair's first row is t = 2*tp
        const int base = (2 * tp - PAD) * C;       // source offset of row t
        const int e0 = 4 * u;                      // element offset within pair
        const float* xb = x + (unsigned)b * TC;

        // If element e >= ROW it belongs to row t+1: source -= (ROW - C).
        const int s0 = base + e0     - (e0     >= ROW ? (ROW - C) : 0);
        const int s1 = base + e0 + 2 - (e0 + 2 >= ROW ? (ROW - C) : 0);

        float2 lo = make_float2(0.0f, 0.0f);
        float2 hi = make_float2(0.0f, 0.0f);
        if (s0 >= 0 && s0 < TC) lo = *reinterpret_cast<const float2*>(xb + s0);
        if (s1 >= 0 && s1 < TC) hi = *reinterpret_cast<const float2*>(xb + s1);

        f32x4 val;
        val.x = lo.x; val.y = lo.y; val.z = hi.x; val.w = hi.y;
        __builtin_nontemporal_store(val, out + v);  // don't evict x from L2
    }
}

extern "C" void kernel_launch(void* const* d_in, const int* in_sizes, int n_in,
                              void* d_out, int out_size, void* d_ws, size_t ws_size,
                              hipStream_t stream) {
    const float* x = (const float*)d_in[0];
    f32x4* out = (f32x4*)d_out;
    OverlapTimeWindowLayer_kernel<<<NWG, 256, 0, stream>>>(x, out);
}